// Round 6
// baseline (208.934 us; speedup 1.0000x reference)
//
#include <hip/hip_runtime.h>
#include <math.h>

// ProjectionLayer: out[b,t,gx,gy] = data[b,t, argmin_n ||locs[b,n]*25+25 - (gx,gy)|| ]
// B=64, T=1024, N=256 sensors, G=50 (2500 grid cells).
// Stage 1 (nearest_k): 41M distance evals -> nearest[b,g] in d_ws (640 KB).
// Stage 2 (gather_lds_k): stage 16 rows in LDS with 4-row-interleaved layout
//   lds[n*4+r]; gather via ds_read_b128 (4 t-values per read, 4x fewer LDS
//   inst), register 4x4 transpose, 655 MB coalesced NT float4 stores.
// R1: scattered GLOBAL loads ~1 lane/cyc in TA -> LDS.      (407->200 us)
// R2/R4: TLP 4->8 blocks/CU NEUTRAL.                        (200->207 us)
// R5: store-drain-free raw barriers NEUTRAL -> drain theory dead. (207 us)
// R6 theory: per-wave ds_read_b32 stream (384/wave/block @ ~9cyc + lgkm
//   waits) serializes with store stream -> cut LDS ops 4x via b128 reads.

#define GRIDG  50
#define GG     2500   // GRIDG*GRIDG
#define GQ     625    // GG/4 (float4 groups per output row)
#define NS     256    // sensors
#define TT     1024
#define BB     64
#define TCHUNK 32     // t rows per block
#define RSTG   16     // rows staged in LDS per barrier (16 KB, 4 tiles of 4 rows)
#define NCH    (TCHUNK / RSTG)   // 2

typedef float f32x4 __attribute__((ext_vector_type(4)));

// post-ds_write barrier: make LDS writes visible, do NOT drain stores
#define BAR_LDS()  asm volatile("s_waitcnt lgkmcnt(0)\n\ts_barrier" ::: "memory")
// post-read barrier: execution sync only (ds_read values already consumed by stores)
#define BAR()      asm volatile("s_barrier" ::: "memory")

// exact replication of reference fp32 arithmetic: unfused mul/add + rounded sqrt
__device__ __forceinline__ float ref_dist(float lx, float ly, float gx, float gy) {
    const float dx = lx - gx;
    const float dy = ly - gy;
    const float s  = __fadd_rn(__fmul_rn(dx, dx), __fmul_rn(dy, dy));
    return __fsqrt_rn(s);
}

// ---- Stage 1: nearest sensor index per grid cell -----------------------------
__global__ __launch_bounds__(256) void nearest_k(const float* __restrict__ locs,
                                                 int* __restrict__ nearest) {
    __shared__ float lsx[NS];
    __shared__ float lsy[NS];
    const int b   = blockIdx.x / 10;   // 10 blocks of 256 cover 2500 cells
    const int gc  = blockIdx.x % 10;
    const int tid = threadIdx.x;

    const float2 l = ((const float2*)locs)[b * NS + tid];
    lsx[tid] = __fadd_rn(__fmul_rn(l.x, 25.0f), 25.0f);
    lsy[tid] = __fadd_rn(__fmul_rn(l.y, 25.0f), 25.0f);
    __syncthreads();

    const int g = gc * 256 + tid;
    if (g >= GG) return;
    const float gx = (float)(g / GRIDG);
    const float gy = (float)(g % GRIDG);

    float best = 1.0e30f;
    int   bi   = 0;
    #pragma unroll 4
    for (int n = 0; n < NS; ++n) {          // ascending n + strict '<'  => first-index
        const float d = ref_dist(lsx[n], lsy[n], gx, gy);   //    tie-break == jnp.argmin
        if (d < best) { best = d; bi = n; }
    }
    nearest[b * GG + g] = bi;
}

// ---- Stage 2: t-interleaved LDS gather (b128 reads, 4x4 reg transpose) ------
__global__ __launch_bounds__(256) void gather_lds_k(const float* __restrict__ data,
                                                    const int* __restrict__ nearest,
                                                    float* __restrict__ out) {
    // layout: tile r4 (4 t-rows) at r4*1024 floats; element (n, rr) at
    // float index r4*1024 + n*4 + rr  ->  f32x4 index r4*256 + n
    __shared__ float rows4[RSTG * NS];   // 16 KB
    const int tid  = threadIdx.x;
    const int wav  = tid >> 6;           // wave w stages rows 4w..4w+3 of chunk
    const int lane = tid & 63;           // sensor group (4 sensors)
    const int b    = blockIdx.y;
    const int t0   = blockIdx.x * TCHUNK;

    // per-thread gather indices (loop-invariant over t) -> registers
    int4 iv[3];
    #pragma unroll
    for (int j = 0; j < 3; ++j) {
        const int gq = tid + j * 256;
        iv[j] = (gq < GQ) ? ((const int4*)nearest)[b * GQ + gq]
                          : make_int4(0, 0, 0, 0);
    }

    const f32x4* __restrict__ dbase = (const f32x4*)data + (size_t)b * TT * (NS / 4);
    f32x4*       __restrict__ obase = (f32x4*)out + (size_t)b * TT * GQ;
    f32x4*       __restrict__ lds4  = (f32x4*)rows4;

    // prologue prefetch: chunk 0 -- wave w loads its 4 rows, 1 f32x4 each
    f32x4 pr[4];
    {
        const f32x4* __restrict__ src = dbase + (size_t)(t0 + 4 * wav) * (NS / 4) + lane;
        #pragma unroll
        for (int rr = 0; rr < 4; ++rr) pr[rr] = src[rr * (NS / 4)];
    }

    for (int c = 0; c < NCH; ++c) {
        // commit prefetched rows to LDS, transposed 4x4 (vmcnt wait lands here,
        // hidden under previous chunk's gather work)
        #pragma unroll
        for (int k = 0; k < 4; ++k) {
            f32x4 w;
            w.x = pr[0][k]; w.y = pr[1][k]; w.z = pr[2][k]; w.w = pr[3][k];
            lds4[wav * 256 + lane * 4 + k] = w;   // sensors 4*lane+k, rows 4w..4w+3
        }
        // issue next chunk's loads before the barrier (T14 issue-early)
        if (c + 1 < NCH) {
            const f32x4* __restrict__ src =
                dbase + (size_t)(t0 + (c + 1) * RSTG + 4 * wav) * (NS / 4) + lane;
            #pragma unroll
            for (int rr = 0; rr < 4; ++rr) pr[rr] = src[rr * (NS / 4)];
        }
        BAR_LDS();   // LDS writes visible; global stores NOT drained

        const int ts = t0 + c * RSTG;
        #pragma unroll
        for (int r4 = 0; r4 < 4; ++r4) {             // 4-row subtiles
            const f32x4* __restrict__ tile = lds4 + r4 * 256;
            #pragma unroll
            for (int j = 0; j < 3; ++j) {
                const int gq = tid + j * 256;
                if (gq < GQ) {
                    // one b128 read per g: sensor iv -> 4 t-values
                    const f32x4 g0 = tile[iv[j].x];
                    const f32x4 g1 = tile[iv[j].y];
                    const f32x4 g2 = tile[iv[j].z];
                    const f32x4 g3 = tile[iv[j].w];
                    #pragma unroll
                    for (int rr = 0; rr < 4; ++rr) { // transpose -> 4 row stores
                        f32x4 v;
                        v.x = g0[rr]; v.y = g1[rr]; v.z = g2[rr]; v.w = g3[rr];
                        __builtin_nontemporal_store(
                            v, &obase[(size_t)(ts + r4 * 4 + rr) * GQ + gq]);
                    }
                }
            }
        }
        BAR();       // reads consumed (by stores) before next chunk's ds_write
    }
}

// ---- Fallback: fused (only if ws too small for the 640 KB index buffer) -----
__global__ __launch_bounds__(256) void fused_k(const float* __restrict__ data,
                                               const float* __restrict__ locs,
                                               float* __restrict__ out) {
    __shared__ float lsx[NS];
    __shared__ float lsy[NS];
    const int b   = blockIdx.z;
    const int tid = threadIdx.x;
    const float2 l = ((const float2*)locs)[b * NS + tid];
    lsx[tid] = __fadd_rn(__fmul_rn(l.x, 25.0f), 25.0f);
    lsy[tid] = __fadd_rn(__fmul_rn(l.y, 25.0f), 25.0f);
    __syncthreads();

    const int gq = blockIdx.x * 256 + tid;
    if (gq >= GQ) return;

    int iv[4];
    #pragma unroll
    for (int k = 0; k < 4; ++k) {
        const int g  = gq * 4 + k;
        const float gx = (float)(g / GRIDG);
        const float gy = (float)(g % GRIDG);
        float best = 1.0e30f;
        int   bi   = 0;
        for (int n = 0; n < NS; ++n) {
            const float d = ref_dist(lsx[n], lsy[n], gx, gy);
            if (d < best) { best = d; bi = n; }
        }
        iv[k] = bi;
    }

    const int t0 = blockIdx.y * (TT / 2);
    const float* __restrict__ dbase = data + (size_t)b * TT * NS;
    float4*      __restrict__ obase = (float4*)out + (size_t)b * TT * GQ + gq;
    #pragma unroll 4
    for (int t = t0; t < t0 + TT / 2; ++t) {
        const float* __restrict__ row = dbase + t * NS;
        float4 v;
        v.x = row[iv[0]];
        v.y = row[iv[1]];
        v.z = row[iv[2]];
        v.w = row[iv[3]];
        obase[(size_t)t * GQ] = v;
    }
}

extern "C" void kernel_launch(void* const* d_in, const int* in_sizes, int n_in,
                              void* d_out, int out_size, void* d_ws, size_t ws_size,
                              hipStream_t stream) {
    const float* data = (const float*)d_in[0];   // [64,1024,256] f32
    const float* locs = (const float*)d_in[1];   // [64,256,2]    f32
    float*       out  = (float*)d_out;           // [64,1024,50,50] f32
    (void)in_sizes; (void)n_in; (void)out_size;

    const size_t idx_bytes = (size_t)BB * GG * sizeof(int);   // 640 KB
    if (ws_size >= idx_bytes) {
        int* nearest = (int*)d_ws;
        nearest_k<<<dim3(BB * 10), 256, 0, stream>>>(locs, nearest);
        gather_lds_k<<<dim3(TT / TCHUNK, BB), 256, 0, stream>>>(data, nearest, out);
    } else {
        fused_k<<<dim3(3, 2, BB), 256, 0, stream>>>(data, locs, out);
    }
}

// Round 7
// 178.723 us; speedup vs baseline: 1.1690x; 1.1690x over previous
//
#include <hip/hip_runtime.h>
#include <math.h>

// ProjectionLayer: out[b,t,gx,gy] = data[b,t, argmin_n ||locs[b,n]*25+25 - (gx,gy)|| ]
// B=64, T=1024, N=256 sensors, G=50 (2500 grid cells).
// Stage 1 (nearest_k): 41M distance evals -> nearest[b,g] in d_ws (640 KB).
// Stage 2 (gather_lds_k): ONE block per CU (256 blocks x 512 thr), each block
//   owns a CONTIGUOUS 2.56 MB output slab; LDS-staged b32 gather; plain
//   coalesced float4 stores. 655 MB writes + 67 MB reads, ~110 us floor.
// R1: scattered GLOBAL loads ~1 lane/cyc in TA -> LDS.      (407->200 us)
// R2/R4: TLP 4->8 blocks/CU NEUTRAL.                        (200->207)
// R5: store-drain-free raw barriers NEUTRAL.                (207)
// R6: 4x fewer LDS ops (b128) NEUTRAL -> LDS exonerated.    (209)
// R7 theory: 1024-2048 concurrent 320KB write streams thrash DRAM pages
//   (fill: few long streams -> 6.7 TB/s; us: ~3.7 TB/s). Fix: 256 long
//   contiguous streams, XCD-contiguous slab mapping, no NT.

#define GRIDG  50
#define GG     2500   // GRIDG*GRIDG
#define GQ     625    // GG/4 (float4 groups per output row)
#define NS     256    // sensors
#define TT     1024
#define BB     64
#define TCHUNK 256    // t rows per block (2.56 MB contiguous slab)
#define RSTG   16     // rows staged in LDS per barrier (16 KB)
#define NCH    (TCHUNK / RSTG)   // 16

// exact replication of reference fp32 arithmetic: unfused mul/add + rounded sqrt
__device__ __forceinline__ float ref_dist(float lx, float ly, float gx, float gy) {
    const float dx = lx - gx;
    const float dy = ly - gy;
    const float s  = __fadd_rn(__fmul_rn(dx, dx), __fmul_rn(dy, dy));
    return __fsqrt_rn(s);
}

// ---- Stage 1: nearest sensor index per grid cell -----------------------------
__global__ __launch_bounds__(256) void nearest_k(const float* __restrict__ locs,
                                                 int* __restrict__ nearest) {
    __shared__ float lsx[NS];
    __shared__ float lsy[NS];
    const int b   = blockIdx.x / 10;   // 10 blocks of 256 cover 2500 cells
    const int gc  = blockIdx.x % 10;
    const int tid = threadIdx.x;

    const float2 l = ((const float2*)locs)[b * NS + tid];
    lsx[tid] = __fadd_rn(__fmul_rn(l.x, 25.0f), 25.0f);
    lsy[tid] = __fadd_rn(__fmul_rn(l.y, 25.0f), 25.0f);
    __syncthreads();

    const int g = gc * 256 + tid;
    if (g >= GG) return;
    const float gx = (float)(g / GRIDG);
    const float gy = (float)(g % GRIDG);

    float best = 1.0e30f;
    int   bi   = 0;
    #pragma unroll 4
    for (int n = 0; n < NS; ++n) {          // ascending n + strict '<'  => first-index
        const float d = ref_dist(lsx[n], lsy[n], gx, gy);   //    tie-break == jnp.argmin
        if (d < best) { best = d; bi = n; }
    }
    nearest[b * GG + g] = bi;
}

// ---- Stage 2: one contiguous output slab per block --------------------------
__global__ __launch_bounds__(512) void gather_lds_k(const float* __restrict__ data,
                                                    const int* __restrict__ nearest,
                                                    float* __restrict__ out) {
    __shared__ float rows[RSTG * NS];   // 16 KB
    const int tid = threadIdx.x;
    const int l   = blockIdx.x;
    // XCD-contiguous slab mapping: XCD k (blocks l%8==k) covers batches
    // [8k, 8k+8) -> one contiguous 80 MB output region per XCD's L2.
    const int sb  = (l & 7) * 32 + (l >> 3);
    const int b   = sb >> 2;               // batch
    const int t0  = (sb & 3) * TCHUNK;     // quarter of T

    // per-thread gather indices (loop-invariant over t) -> registers
    const int4 iv0 = ((const int4*)nearest)[b * GQ + tid];          // tid<512<=GQ
    const int4 iv1 = (tid < GQ - 512)
                   ? ((const int4*)nearest)[b * GQ + 512 + tid]
                   : make_int4(0, 0, 0, 0);

    const float4* __restrict__ dbase = (const float4*)data + (size_t)b * TT * (NS / 4);
    float4*       __restrict__ obase = (float4*)out + (size_t)b * TT * GQ;

    // prologue prefetch: chunk 0 (16 rows = 1024 float4 = 2/thread, coalesced)
    const float4* __restrict__ src = dbase + (size_t)t0 * (NS / 4);
    float4 pr0 = src[tid];
    float4 pr1 = src[tid + 512];

    for (int c = 0; c < NCH; ++c) {
        __syncthreads();   // previous chunk fully consumed
        ((float4*)rows)[tid]       = pr0;
        ((float4*)rows)[tid + 512] = pr1;
        // issue next chunk's loads early (in flight across the gather below)
        if (c + 1 < NCH) {
            src += RSTG * (NS / 4);
            pr0 = src[tid];
            pr1 = src[tid + 512];
        }
        __syncthreads();   // staged rows visible

        const int ts = t0 + c * RSTG;
        #pragma unroll
        for (int r = 0; r < RSTG; ++r) {
            const float* __restrict__ row  = rows + r * NS;
            float4*      __restrict__ orow = obase + (size_t)(ts + r) * GQ;
            float4 v;
            v.x = row[iv0.x];
            v.y = row[iv0.y];
            v.z = row[iv0.z];
            v.w = row[iv0.w];
            orow[tid] = v;                          // coalesced 16B/lane store
            if (tid < GQ - 512) {
                float4 u;
                u.x = row[iv1.x];
                u.y = row[iv1.y];
                u.z = row[iv1.z];
                u.w = row[iv1.w];
                orow[512 + tid] = u;
            }
        }
    }
}

// ---- Fallback: fused (only if ws too small for the 640 KB index buffer) -----
__global__ __launch_bounds__(256) void fused_k(const float* __restrict__ data,
                                               const float* __restrict__ locs,
                                               float* __restrict__ out) {
    __shared__ float lsx[NS];
    __shared__ float lsy[NS];
    const int b   = blockIdx.z;
    const int tid = threadIdx.x;
    const float2 l = ((const float2*)locs)[b * NS + tid];
    lsx[tid] = __fadd_rn(__fmul_rn(l.x, 25.0f), 25.0f);
    lsy[tid] = __fadd_rn(__fmul_rn(l.y, 25.0f), 25.0f);
    __syncthreads();

    const int gq = blockIdx.x * 256 + tid;
    if (gq >= GQ) return;

    int iv[4];
    #pragma unroll
    for (int k = 0; k < 4; ++k) {
        const int g  = gq * 4 + k;
        const float gx = (float)(g / GRIDG);
        const float gy = (float)(g % GRIDG);
        float best = 1.0e30f;
        int   bi   = 0;
        for (int n = 0; n < NS; ++n) {
            const float d = ref_dist(lsx[n], lsy[n], gx, gy);
            if (d < best) { best = d; bi = n; }
        }
        iv[k] = bi;
    }

    const int t0 = blockIdx.y * (TT / 2);
    const float* __restrict__ dbase = data + (size_t)b * TT * NS;
    float4*      __restrict__ obase = (float4*)out + (size_t)b * TT * GQ + gq;
    #pragma unroll 4
    for (int t = t0; t < t0 + TT / 2; ++t) {
        const float* __restrict__ row = dbase + t * NS;
        float4 v;
        v.x = row[iv[0]];
        v.y = row[iv[1]];
        v.z = row[iv[2]];
        v.w = row[iv[3]];
        obase[(size_t)t * GQ] = v;
    }
}

extern "C" void kernel_launch(void* const* d_in, const int* in_sizes, int n_in,
                              void* d_out, int out_size, void* d_ws, size_t ws_size,
                              hipStream_t stream) {
    const float* data = (const float*)d_in[0];   // [64,1024,256] f32
    const float* locs = (const float*)d_in[1];   // [64,256,2]    f32
    float*       out  = (float*)d_out;           // [64,1024,50,50] f32
    (void)in_sizes; (void)n_in; (void)out_size;

    const size_t idx_bytes = (size_t)BB * GG * sizeof(int);   // 640 KB
    if (ws_size >= idx_bytes) {
        int* nearest = (int*)d_ws;
        nearest_k<<<dim3(BB * 10), 256, 0, stream>>>(locs, nearest);
        gather_lds_k<<<dim3(BB * 4), 512, 0, stream>>>(data, nearest, out);
    } else {
        fused_k<<<dim3(3, 2, BB), 256, 0, stream>>>(data, locs, out);
    }
}